// Round 15
// baseline (73.118 us; speedup 1.0000x reference)
//
#include <hip/hip_runtime.h>
#include <hip/hip_fp16.h>

// CapsuleLinear, B=32, I=512, L=64, O=128, J=64, 3 routing iterations.
// Algebraic fusion (no priors): out = W_o @ xc, wn = (G_o @ xc)/||W_o xc||,
// G_o = W_o^T W_o (fp16 lane-major Gq, 1 MB in d_ws).
// r15: OCCUPANCY. r14's xT was a pointless LDS round-trip (each lane read
// back exactly the 4 uint4 it wrote) -> phase-B B-frags now live in 4 named
// uint4 registers (bt0-3, 16 VGPRs). That frees 64K LDS -> OPB=8, NT=1024,
// grid=512, 77.3 KB LDS -> 2 blocks/CU (32 waves/CU), one resident round.
// __launch_bounds__(1024,8) pins the 64-VGPR tier; persistent regs = 24.
// coefT/xcpart overlay (barrier-separated, r13-proven). Phase-A A-frags are
// re-read from xs per pass (cheap conflict-free b128; xs stays alive).
// Scale invariance (r13): softmax denominator applied only on the last pass.

#define CB 32
#define CI 512
#define CL 64
#define CO 128
#define OPB 8
#define NT 1024

typedef _Float16 half8 __attribute__((ext_vector_type(8)));
typedef float f32x4 __attribute__((ext_vector_type(4)));

static __device__ __forceinline__ _Float16 half_sel(uint v, int sh) {
  union { unsigned short s; _Float16 h; } c;
  c.s = (unsigned short)(v >> sh);
  return c.h;
}

// Gq layout (16B units): unit u = (o*8 + k)*64 + l1 holds pairs p=4k+q for
// ROW l1 (symmetric == column l1): (G[o][l1][8k+2q], G[o][l1][8k+2q+1]).
__global__ __launch_bounds__(256) void caps_gram(const float* __restrict__ wg,
                                                 __half2* __restrict__ Gq) {
  const int o = blockIdx.x;
  const int h = blockIdx.y;        // l1-half: rows h*32 .. h*32+31
  const int t = threadIdx.x;
  __shared__ float wl[64 * 65];    // W[o] padded (+1 col)
#pragma unroll
  for (int k = 0; k < 16; ++k) {
    int f = t + 256 * k;
    int j = f >> 6, l = f & 63;
    wl[j * 65 + l] = wg[(o << 12) + f];
  }
  __syncthreads();
  const int l1 = h * 32 + (t >> 3);
  const int kq = t & 7;
  const int l2b = kq << 3;
  float acc[8];
#pragma unroll
  for (int m = 0; m < 8; ++m) acc[m] = 0.f;
#pragma unroll 4
  for (int j = 0; j < 64; ++j) {
    float wa = wl[j * 65 + l1];
#pragma unroll
    for (int m = 0; m < 8; ++m) acc[m] += wa * wl[j * 65 + l2b + m];
  }
  union { __half2 h2[4]; uint4 u; } pk;
#pragma unroll
  for (int q = 0; q < 4; ++q)
    pk.h2[q] = __floats2half2_rn(acc[2 * q], acc[2 * q + 1]);
  reinterpret_cast<uint4*>(Gq)[(o << 9) + (kq << 6) + l1] = pk.u;
}

__global__ __launch_bounds__(NT, 8) void caps_main(const float* __restrict__ xg,
                                                   const float* __restrict__ wg,
                                                   const __half2* __restrict__ Gq,
                                                   float* __restrict__ outg) {
  const int b = blockIdx.y;
  const int obase = blockIdx.x * OPB;
  const int t = threadIdx.x;
  const int w = t >> 6;          // wave 0..15
  const int lane = t & 63;
  const int g = lane >> 4;
  const int o15 = lane & 15;
  const int oc = o15 & 7;        // clamped capsule index (8 valid o's)

  __shared__ __align__(16) _Float16 xs[CI * CL];      // 65536 B (alive: A-frags)
  __shared__ __align__(16) _Float16 cfx[OPB * CI];    // 8192 B coefT∪xcpart
  __shared__ __align__(16) _Float16 wn16[OPB * CL];   // 1024 B (swizzled)
  __shared__ __align__(16) float xc_s[OPB * CL];      // 2048 B
  __shared__ float se_part[16 * OPB];                 // 512 B (pass 3 only)
  float* const xcpart = reinterpret_cast<float*>(cfx);  // [4][8][64] f32 = 8K
  char* const xs_b = reinterpret_cast<char*>(xs);
  char* const cf_b = reinterpret_cast<char*>(cfx);
  char* const wn_b = reinterpret_cast<char*>(wn16);
  // total 77312 B -> 2 blocks/CU; grid 512 = one full-chip resident round

  const int qh = w >> 2, nt = w & 3;  // phase-B: K-quarter, l-subtile
  const int lcol = nt * 16 + o15;     // this lane's l index in phase B

  // G row pointer (16B units, coalesced across lanes); only waves 0-7 use it
  const uint4* Gp = reinterpret_cast<const uint4*>(Gq) +
                    ((obase + (w & 7)) << 9) + lane;
  uint4 ga0, ga1;  // G double-buffer head (8 regs across barriers)

  // ---- stage x[b] -> fp16 subtiled LDS; coalesced float4 global reads ----
  {
    const float4* xg4 = reinterpret_cast<const float4*>(xg + b * (CI * CL));
#pragma unroll
    for (int k = 0; k < 4; ++k) {
      int f = t + NT * k;        // 8-half unit id: row i, l-unit lu
      int i = f >> 3, lu = f & 7;
      float4 a = xg4[2 * f];
      float4 c = xg4[2 * f + 1];
      union { _Float16 h[8]; uint4 u; } cv;
      cv.h[0] = (_Float16)a.x; cv.h[1] = (_Float16)a.y;
      cv.h[2] = (_Float16)a.z; cv.h[3] = (_Float16)a.w;
      cv.h[4] = (_Float16)c.x; cv.h[5] = (_Float16)c.y;
      cv.h[6] = (_Float16)c.z; cv.h[7] = (_Float16)c.w;
      int off = ((i >> 4) * 4 + (lu >> 1)) * 512 + (i & 15) * 32 + (lu & 1) * 16;
      *reinterpret_cast<uint4*>(xs_b + off) = cv.u;
    }
  }
  __syncthreads();

  // ---- setup: B-frags into 4 named uint4 (NO xT round-trip) + xbar ----
  // btK holds x[i = qh*256 + (16K+4g..+3)*? ..][lcol] column fragment:
  // btK.h[j] = x[qh*256 + (K*4+g)*8 + j][lcol]
  uint4 bt0, bt1, bt2, bt3;
  float xbs = 0.f;
  {
    const uint* xrd32 = reinterpret_cast<const uint*>(
                            xs_b + nt * 512 + ((o15 & 8) << 1)) +
                        ((o15 & 7) >> 1);
    const int sh = (o15 & 1) << 4;
#define GATHW(K, BT)                                                        \
  {                                                                         \
    int P = qh * 16 + (K)*4 + g;                                            \
    const uint* xk = xrd32 + (P >> 1) * 512 + (P & 1) * 64;                 \
    uint d0 = xk[0], d1 = xk[8], d2 = xk[16], d3 = xk[24];                  \
    uint d4 = xk[32], d5 = xk[40], d6 = xk[48], d7 = xk[56];                \
    union { _Float16 h[8]; uint4 u; } fv;                                   \
    fv.h[0] = half_sel(d0, sh); fv.h[1] = half_sel(d1, sh);                 \
    fv.h[2] = half_sel(d2, sh); fv.h[3] = half_sel(d3, sh);                 \
    fv.h[4] = half_sel(d4, sh); fv.h[5] = half_sel(d5, sh);                 \
    fv.h[6] = half_sel(d6, sh); fv.h[7] = half_sel(d7, sh);                 \
    xbs += (float)fv.h[0] + (float)fv.h[1] + (float)fv.h[2] +               \
           (float)fv.h[3] + (float)fv.h[4] + (float)fv.h[5] +               \
           (float)fv.h[6] + (float)fv.h[7];                                 \
    BT = fv.u;                                                              \
  }
    GATHW(0, bt0) GATHW(1, bt1) GATHW(2, bt2) GATHW(3, bt3)
#undef GATHW
    xbs += __shfl_xor(xbs, 16, 64);
    xbs += __shfl_xor(xbs, 32, 64);
    if (g == 0) xcpart[qh * 512 + lcol] = xbs;  // xbar partial at [qh][0][l]
    if (w < 8) { ga0 = Gp[0]; ga1 = Gp[64]; }   // pass-0 G head
  }
  __syncthreads();

  for (int pass = 0; pass < 4; ++pass) {
    if (pass > 0) {
      // ---- phase A: logits for 8 o's via MFMA; exp -> coefT ----
      half8 bw0 = *reinterpret_cast<const half8*>(
          wn_b + oc * 128 + ((g ^ oc) << 4));
      half8 bw1 = *reinterpret_cast<const half8*>(
          wn_b + oc * 128 + (((4 + g) ^ oc) << 4));
      float sacc = 0.f;
#pragma unroll
      for (int ti = 0; ti < 2; ++ti) {
        const int st = 2 * w + ti;            // i-subtile, rows st*16..+15
        const int itb = st * 2048;
        const int abase = o15 * 32 + ((g & 1) << 4);
        half8 a0 = *reinterpret_cast<const half8*>(
            xs_b + itb + ((g >> 1) * 512) + abase);
        half8 a1 = *reinterpret_cast<const half8*>(
            xs_b + itb + ((2 + (g >> 1)) * 512) + abase);
        f32x4 d = {0.f, 0.f, 0.f, 0.f};
        d = __builtin_amdgcn_mfma_f32_16x16x32_f16(a0, bw0, d, 0, 0, 0);
        d = __builtin_amdgcn_mfma_f32_16x16x32_f16(a1, bw1, d, 0, 0, 0);
        // |logits| <= ||x_i||*sigma_max(W) ~ 2.5: softmax w/o max-sub is safe
        float e0 = __expf(d[0]), e1 = __expf(d[1]);
        float e2 = __expf(d[2]), e3 = __expf(d[3]);
        sacc += (e0 + e1) + (e2 + e3);
        if (o15 < 8) {  // valid capsule columns only
          int p = st * 2 + (g >> 1);
          union { _Float16 h[4]; uint2 u; } pk;
          pk.h[0] = (_Float16)e0; pk.h[1] = (_Float16)e1;
          pk.h[2] = (_Float16)e2; pk.h[3] = (_Float16)e3;
          *reinterpret_cast<uint2*>(cf_b + o15 * 1024 + ((p ^ o15) << 4) +
                                    ((g & 1) << 3)) = pk.u;
        }
      }
      if (pass == 3) {  // softmax denominator only needed on the final pass
        sacc += __shfl_xor(sacc, 16, 64);
        sacc += __shfl_xor(sacc, 32, 64);
        if (lane < 8) se_part[w * 8 + lane] = sacc;  // [i-wave][o]
      }
      __syncthreads();  // (1) coefT ready

      // ---- phase B: xc partials via MFMA (A=coefT b128, B=bt regs) ----
      if (w < 8 && pass < 3) { ga0 = Gp[0]; ga1 = Gp[64]; }  // G in flight
      f32x4 d = {0.f, 0.f, 0.f, 0.f};
#define MFMAK(K, BT)                                                        \
  {                                                                         \
    int p = qh * 16 + (K)*4 + g;                                            \
    half8 a = *reinterpret_cast<const half8*>(cf_b + oc * 1024 +            \
                                              ((p ^ oc) << 4));             \
    d = __builtin_amdgcn_mfma_f32_16x16x32_f16(                             \
        a, *reinterpret_cast<const half8*>(&BT), d, 0, 0, 0);               \
  }
      MFMAK(0, bt0) MFMAK(1, bt1) MFMAK(2, bt2) MFMAK(3, bt3)
#undef MFMAK
      __syncthreads();  // (2) all coefT reads done before overlay write
      if (g < 2) {      // D rows 0-7 (valid o) live in lanes 0-31
#pragma unroll
        for (int r = 0; r < 4; ++r)
          xcpart[qh * 512 + (g * 4 + r) * 64 + lcol] = d[r];  // [q][o][l]
      }
      __syncthreads();  // (3) partials ready
    }

    // ---- finalize (waves 0-7): xc; wn = G xc/||W xc|| (skip pass 3) ----
    if (w < 8) {
      float sxc;
      if (pass == 0) {
        sxc = xcpart[lane] + xcpart[512 + lane] + xcpart[1024 + lane] +
              xcpart[1536 + lane];
      } else {
        sxc = xcpart[w * 64 + lane] + xcpart[512 + w * 64 + lane] +
              xcpart[1024 + w * 64 + lane] + xcpart[1536 + w * 64 + lane];
      }
      float xcv;
      if (pass == 3) {  // apply softmax denominator once at the end
        float sp = se_part[(lane & 15) * 8 + w];
        sp += __shfl_xor(sp, 1, 64);
        sp += __shfl_xor(sp, 2, 64);
        sp += __shfl_xor(sp, 4, 64);
        sp += __shfl_xor(sp, 8, 64);
        xcv = sxc / sp;
      } else {
        xcv = sxc;  // unnormalized: scale cancels inside wn
      }
      xc_s[(w << 6) + lane] = xcv;
      if (pass < 3) {
        const float4* xc4 = reinterpret_cast<const float4*>(&xc_s[w << 6]);
        float u0 = 0.f, u1 = 0.f, u2 = 0.f, u3 = 0.f;
#define GDOT(V, K)                                                          \
  {                                                                         \
    float4 xa = xc4[2 * (K)], xb = xc4[2 * (K) + 1];                        \
    float2 h0 = __half22float2(*reinterpret_cast<const __half2*>(&V.x));    \
    float2 h1 = __half22float2(*reinterpret_cast<const __half2*>(&V.y));    \
    float2 h2 = __half22float2(*reinterpret_cast<const __half2*>(&V.z));    \
    float2 h3 = __half22float2(*reinterpret_cast<const __half2*>(&V.w));    \
    u0 += h0.x * xa.x; u1 += h0.y * xa.y;                                   \
    u2 += h1.x * xa.z; u3 += h1.y * xa.w;                                   \
    u0 += h2.x * xb.x; u1 += h2.y * xb.y;                                   \
    u2 += h3.x * xb.z; u3 += h3.y * xb.w;                                   \
  }
        // double-buffered G: <=16 G regs live, loads hidden under GDOTs
        uint4 gb0 = Gp[128], gb1 = Gp[192];
        GDOT(ga0, 0) GDOT(ga1, 1)
        ga0 = Gp[256]; ga1 = Gp[320];
        GDOT(gb0, 2) GDOT(gb1, 3)
        gb0 = Gp[384]; gb1 = Gp[448];
        GDOT(ga0, 4) GDOT(ga1, 5)
        GDOT(gb0, 6) GDOT(gb1, 7)
#undef GDOT
        float uv = (u0 + u1) + (u2 + u3);
        float sq = uv * xcv;
#pragma unroll
        for (int m = 32; m; m >>= 1) sq += __shfl_xor(sq, m, 64);
        float wnv = uv / fmaxf(sqrtf(fmaxf(sq, 0.f)), 1e-12f);
        union { _Float16 hf; unsigned short us; } wc;
        wc.hf = (_Float16)wnv;
        *reinterpret_cast<unsigned short*>(
            wn_b + w * 128 + (((lane >> 3) ^ w) << 4) + ((lane & 7) << 1)) =
            wc.us;
      }
    }
    __syncthreads();  // (4) wn / final xc ready
  }

  // ---- epilogue (waves 0-7): out[b, obase+w, j=lane] = W[o][j][:]·xc ----
  if (w < 8) {
    const float* Wp = wg + ((((obase + w) << 6) + lane) << 6);
    float a0 = 0.f, a1 = 0.f, a2 = 0.f, a3 = 0.f;
#pragma unroll
    for (int k = 0; k < 16; ++k) {
      float4 wv = *reinterpret_cast<const float4*>(&Wp[k << 2]);
      float4 xv = *reinterpret_cast<const float4*>(&xc_s[(w << 6) + (k << 2)]);
      a0 += wv.x * xv.x; a1 += wv.y * xv.y;
      a2 += wv.z * xv.z; a3 += wv.w * xv.w;
    }
    outg[((b << 7) + obase + w) * 64 + lane] = (a0 + a1) + (a2 + a3);
  }
}

extern "C" void kernel_launch(void* const* d_in, const int* in_sizes, int n_in,
                              void* d_out, int out_size, void* d_ws, size_t ws_size,
                              hipStream_t stream) {
  const float* x = (const float*)d_in[0];     // (32, 512, 64) fp32
  const float* wgt = (const float*)d_in[1];   // (128, 64, 64) fp32
  float* out = (float*)d_out;                 // (32, 128, 64) fp32
  __half2* Gq = (__half2*)d_ws;               // 128*8*64 x 16B = 1 MB

  caps_gram<<<dim3(CO, 2), dim3(256), 0, stream>>>(wgt, Gq);
  caps_main<<<dim3(CO / OPB, CB), dim3(NT), 0, stream>>>(x, wgt, Gq, out);
}

// Round 16
// 40.071 us; speedup vs baseline: 1.8247x; 1.8247x over previous
//
#include <hip/hip_runtime.h>
#include <hip/hip_fp16.h>

// CapsuleLinear, B=32, I=512, L=64, O=128, J=64, 3 routing iterations.
// Algebraic fusion (no priors): out = W_o @ xc, wn = (G_o @ xc)/||W_o xc||,
// G_o = W_o^T W_o (fp16 lane-major Gq, 1 MB in d_ws).
// r16 = r15 structure (passed, absmax 1.22e-4) with ONE change: the register
// tier is pinned via __attribute__((amdgpu_num_vgpr(64))) instead of
// __launch_bounds__(NT,8). r15's counters showed the allocator chose the
// 32-VGPR tier under (1024,8) and spilled everything (FETCH 103MB, WRITE
// 108MB). Demand here is ~56-60 VGPRs: bt0-3 (16) + ga/gb (<=16) + temps.
// Structure: OPB=8, NT=1024, grid=512, 77.3 KB LDS -> 2 blocks/CU
// (8 waves/SIMD, 2x r14's latency-hiding). B-frags in registers (no xT).
// Scale invariance: softmax denominator applied only on the last pass.

#define CB 32
#define CI 512
#define CL 64
#define CO 128
#define OPB 8
#define NT 1024

typedef _Float16 half8 __attribute__((ext_vector_type(8)));
typedef float f32x4 __attribute__((ext_vector_type(4)));

static __device__ __forceinline__ _Float16 half_sel(uint v, int sh) {
  union { unsigned short s; _Float16 h; } c;
  c.s = (unsigned short)(v >> sh);
  return c.h;
}

// Gq layout (16B units): unit u = (o*8 + k)*64 + l1 holds pairs p=4k+q for
// ROW l1 (symmetric == column l1): (G[o][l1][8k+2q], G[o][l1][8k+2q+1]).
__global__ __launch_bounds__(256) void caps_gram(const float* __restrict__ wg,
                                                 __half2* __restrict__ Gq) {
  const int o = blockIdx.x;
  const int h = blockIdx.y;        // l1-half: rows h*32 .. h*32+31
  const int t = threadIdx.x;
  __shared__ float wl[64 * 65];    // W[o] padded (+1 col)
#pragma unroll
  for (int k = 0; k < 16; ++k) {
    int f = t + 256 * k;
    int j = f >> 6, l = f & 63;
    wl[j * 65 + l] = wg[(o << 12) + f];
  }
  __syncthreads();
  const int l1 = h * 32 + (t >> 3);
  const int kq = t & 7;
  const int l2b = kq << 3;
  float acc[8];
#pragma unroll
  for (int m = 0; m < 8; ++m) acc[m] = 0.f;
#pragma unroll 4
  for (int j = 0; j < 64; ++j) {
    float wa = wl[j * 65 + l1];
#pragma unroll
    for (int m = 0; m < 8; ++m) acc[m] += wa * wl[j * 65 + l2b + m];
  }
  union { __half2 h2[4]; uint4 u; } pk;
#pragma unroll
  for (int q = 0; q < 4; ++q)
    pk.h2[q] = __floats2half2_rn(acc[2 * q], acc[2 * q + 1]);
  reinterpret_cast<uint4*>(Gq)[(o << 9) + (kq << 6) + l1] = pk.u;
}

__global__ __launch_bounds__(NT)
__attribute__((amdgpu_num_vgpr(64)))
void caps_main(const float* __restrict__ xg,
               const float* __restrict__ wg,
               const __half2* __restrict__ Gq,
               float* __restrict__ outg) {
  const int b = blockIdx.y;
  const int obase = blockIdx.x * OPB;
  const int t = threadIdx.x;
  const int w = t >> 6;          // wave 0..15
  const int lane = t & 63;
  const int g = lane >> 4;
  const int o15 = lane & 15;
  const int oc = o15 & 7;        // clamped capsule index (8 valid o's)

  __shared__ __align__(16) _Float16 xs[CI * CL];      // 65536 B (alive: A-frags)
  __shared__ __align__(16) _Float16 cfx[OPB * CI];    // 8192 B coefT∪xcpart
  __shared__ __align__(16) _Float16 wn16[OPB * CL];   // 1024 B (swizzled)
  __shared__ __align__(16) float xc_s[OPB * CL];      // 2048 B
  __shared__ float se_part[16 * OPB];                 // 512 B (pass 3 only)
  float* const xcpart = reinterpret_cast<float*>(cfx);  // [4][8][64] f32 = 8K
  char* const xs_b = reinterpret_cast<char*>(xs);
  char* const cf_b = reinterpret_cast<char*>(cfx);
  char* const wn_b = reinterpret_cast<char*>(wn16);
  // total 77312 B -> 2 blocks/CU; grid 512 = one full-chip resident round

  const int qh = w >> 2, nt = w & 3;  // phase-B: K-quarter, l-subtile
  const int lcol = nt * 16 + o15;     // this lane's l index in phase B

  // G row pointer (16B units, coalesced across lanes); only waves 0-7 use it
  const uint4* Gp = reinterpret_cast<const uint4*>(Gq) +
                    ((obase + (w & 7)) << 9) + lane;
  uint4 ga0, ga1;  // G double-buffer head (8 regs across barriers)

  // ---- stage x[b] -> fp16 subtiled LDS; coalesced float4 global reads ----
  {
    const float4* xg4 = reinterpret_cast<const float4*>(xg + b * (CI * CL));
#pragma unroll
    for (int k = 0; k < 4; ++k) {
      int f = t + NT * k;        // 8-half unit id: row i, l-unit lu
      int i = f >> 3, lu = f & 7;
      float4 a = xg4[2 * f];
      float4 c = xg4[2 * f + 1];
      union { _Float16 h[8]; uint4 u; } cv;
      cv.h[0] = (_Float16)a.x; cv.h[1] = (_Float16)a.y;
      cv.h[2] = (_Float16)a.z; cv.h[3] = (_Float16)a.w;
      cv.h[4] = (_Float16)c.x; cv.h[5] = (_Float16)c.y;
      cv.h[6] = (_Float16)c.z; cv.h[7] = (_Float16)c.w;
      int off = ((i >> 4) * 4 + (lu >> 1)) * 512 + (i & 15) * 32 + (lu & 1) * 16;
      *reinterpret_cast<uint4*>(xs_b + off) = cv.u;
    }
  }
  __syncthreads();

  // ---- setup: B-frags into 4 named uint4 + xbar partials ----
  // btK.h[j] = x[qh*256 + (K*4+g)*8 + j][lcol]
  uint4 bt0, bt1, bt2, bt3;
  float xbs = 0.f;
  {
    const uint* xrd32 = reinterpret_cast<const uint*>(
                            xs_b + nt * 512 + ((o15 & 8) << 1)) +
                        ((o15 & 7) >> 1);
    const int sh = (o15 & 1) << 4;
#define GATHW(K, BT)                                                        \
  {                                                                         \
    int P = qh * 16 + (K)*4 + g;                                            \
    const uint* xk = xrd32 + (P >> 1) * 512 + (P & 1) * 64;                 \
    uint d0 = xk[0], d1 = xk[8], d2 = xk[16], d3 = xk[24];                  \
    uint d4 = xk[32], d5 = xk[40], d6 = xk[48], d7 = xk[56];                \
    union { _Float16 h[8]; uint4 u; } fv;                                   \
    fv.h[0] = half_sel(d0, sh); fv.h[1] = half_sel(d1, sh);                 \
    fv.h[2] = half_sel(d2, sh); fv.h[3] = half_sel(d3, sh);                 \
    fv.h[4] = half_sel(d4, sh); fv.h[5] = half_sel(d5, sh);                 \
    fv.h[6] = half_sel(d6, sh); fv.h[7] = half_sel(d7, sh);                 \
    xbs += (float)fv.h[0] + (float)fv.h[1] + (float)fv.h[2] +               \
           (float)fv.h[3] + (float)fv.h[4] + (float)fv.h[5] +               \
           (float)fv.h[6] + (float)fv.h[7];                                 \
    BT = fv.u;                                                              \
  }
    GATHW(0, bt0) GATHW(1, bt1) GATHW(2, bt2) GATHW(3, bt3)
#undef GATHW
    xbs += __shfl_xor(xbs, 16, 64);
    xbs += __shfl_xor(xbs, 32, 64);
    if (g == 0) xcpart[qh * 512 + lcol] = xbs;  // xbar partial at [qh][0][l]
    if (w < 8) { ga0 = Gp[0]; ga1 = Gp[64]; }   // pass-0 G head
  }
  __syncthreads();

  for (int pass = 0; pass < 4; ++pass) {
    if (pass > 0) {
      // ---- phase A: logits for 8 o's via MFMA; exp -> coefT ----
      half8 bw0 = *reinterpret_cast<const half8*>(
          wn_b + oc * 128 + ((g ^ oc) << 4));
      half8 bw1 = *reinterpret_cast<const half8*>(
          wn_b + oc * 128 + (((4 + g) ^ oc) << 4));
      float sacc = 0.f;
#pragma unroll
      for (int ti = 0; ti < 2; ++ti) {
        const int st = 2 * w + ti;            // i-subtile, rows st*16..+15
        const int itb = st * 2048;
        const int abase = o15 * 32 + ((g & 1) << 4);
        half8 a0 = *reinterpret_cast<const half8*>(
            xs_b + itb + ((g >> 1) * 512) + abase);
        half8 a1 = *reinterpret_cast<const half8*>(
            xs_b + itb + ((2 + (g >> 1)) * 512) + abase);
        f32x4 d = {0.f, 0.f, 0.f, 0.f};
        d = __builtin_amdgcn_mfma_f32_16x16x32_f16(a0, bw0, d, 0, 0, 0);
        d = __builtin_amdgcn_mfma_f32_16x16x32_f16(a1, bw1, d, 0, 0, 0);
        // |logits| <= ||x_i||*sigma_max(W) ~ 2.5: softmax w/o max-sub is safe
        float e0 = __expf(d[0]), e1 = __expf(d[1]);
        float e2 = __expf(d[2]), e3 = __expf(d[3]);
        sacc += (e0 + e1) + (e2 + e3);
        if (o15 < 8) {  // valid capsule columns only
          int p = st * 2 + (g >> 1);
          union { _Float16 h[4]; uint2 u; } pk;
          pk.h[0] = (_Float16)e0; pk.h[1] = (_Float16)e1;
          pk.h[2] = (_Float16)e2; pk.h[3] = (_Float16)e3;
          *reinterpret_cast<uint2*>(cf_b + o15 * 1024 + ((p ^ o15) << 4) +
                                    ((g & 1) << 3)) = pk.u;
        }
      }
      if (pass == 3) {  // softmax denominator only needed on the final pass
        sacc += __shfl_xor(sacc, 16, 64);
        sacc += __shfl_xor(sacc, 32, 64);
        if (lane < 8) se_part[w * 8 + lane] = sacc;  // [i-wave][o]
      }
      __syncthreads();  // (1) coefT ready

      // ---- phase B: xc partials via MFMA (A=coefT b128, B=bt regs) ----
      if (w < 8 && pass < 3) { ga0 = Gp[0]; ga1 = Gp[64]; }  // G in flight
      f32x4 d = {0.f, 0.f, 0.f, 0.f};
#define MFMAK(K, BT)                                                        \
  {                                                                         \
    int p = qh * 16 + (K)*4 + g;                                            \
    half8 a = *reinterpret_cast<const half8*>(cf_b + oc * 1024 +            \
                                              ((p ^ oc) << 4));             \
    d = __builtin_amdgcn_mfma_f32_16x16x32_f16(                             \
        a, *reinterpret_cast<const half8*>(&BT), d, 0, 0, 0);               \
  }
      MFMAK(0, bt0) MFMAK(1, bt1) MFMAK(2, bt2) MFMAK(3, bt3)
#undef MFMAK
      __syncthreads();  // (2) all coefT reads done before overlay write
      if (g < 2) {      // D rows 0-7 (valid o) live in lanes 0-31
#pragma unroll
        for (int r = 0; r < 4; ++r)
          xcpart[qh * 512 + (g * 4 + r) * 64 + lcol] = d[r];  // [q][o][l]
      }
      __syncthreads();  // (3) partials ready
    }

    // ---- finalize (waves 0-7): xc; wn = G xc/||W xc|| (skip pass 3) ----
    if (w < 8) {
      float sxc;
      if (pass == 0) {
        sxc = xcpart[lane] + xcpart[512 + lane] + xcpart[1024 + lane] +
              xcpart[1536 + lane];
      } else {
        sxc = xcpart[w * 64 + lane] + xcpart[512 + w * 64 + lane] +
              xcpart[1024 + w * 64 + lane] + xcpart[1536 + w * 64 + lane];
      }
      float xcv;
      if (pass == 3) {  // apply softmax denominator once at the end
        float sp = se_part[(lane & 15) * 8 + w];
        sp += __shfl_xor(sp, 1, 64);
        sp += __shfl_xor(sp, 2, 64);
        sp += __shfl_xor(sp, 4, 64);
        sp += __shfl_xor(sp, 8, 64);
        xcv = sxc / sp;
      } else {
        xcv = sxc;  // unnormalized: scale cancels inside wn
      }
      xc_s[(w << 6) + lane] = xcv;
      if (pass < 3) {
        const float4* xc4 = reinterpret_cast<const float4*>(&xc_s[w << 6]);
        float u0 = 0.f, u1 = 0.f, u2 = 0.f, u3 = 0.f;
#define GDOT(V, K)                                                          \
  {                                                                         \
    float4 xa = xc4[2 * (K)], xb = xc4[2 * (K) + 1];                        \
    float2 h0 = __half22float2(*reinterpret_cast<const __half2*>(&V.x));    \
    float2 h1 = __half22float2(*reinterpret_cast<const __half2*>(&V.y));    \
    float2 h2 = __half22float2(*reinterpret_cast<const __half2*>(&V.z));    \
    float2 h3 = __half22float2(*reinterpret_cast<const __half2*>(&V.w));    \
    u0 += h0.x * xa.x; u1 += h0.y * xa.y;                                   \
    u2 += h1.x * xa.z; u3 += h1.y * xa.w;                                   \
    u0 += h2.x * xb.x; u1 += h2.y * xb.y;                                   \
    u2 += h3.x * xb.z; u3 += h3.y * xb.w;                                   \
  }
        // double-buffered G: <=16 G regs live, loads hidden under GDOTs
        uint4 gb0 = Gp[128], gb1 = Gp[192];
        GDOT(ga0, 0) GDOT(ga1, 1)
        ga0 = Gp[256]; ga1 = Gp[320];
        GDOT(gb0, 2) GDOT(gb1, 3)
        gb0 = Gp[384]; gb1 = Gp[448];
        GDOT(ga0, 4) GDOT(ga1, 5)
        GDOT(gb0, 6) GDOT(gb1, 7)
#undef GDOT
        float uv = (u0 + u1) + (u2 + u3);
        float sq = uv * xcv;
#pragma unroll
        for (int m = 32; m; m >>= 1) sq += __shfl_xor(sq, m, 64);
        float wnv = uv / fmaxf(sqrtf(fmaxf(sq, 0.f)), 1e-12f);
        union { _Float16 hf; unsigned short us; } wc;
        wc.hf = (_Float16)wnv;
        *reinterpret_cast<unsigned short*>(
            wn_b + w * 128 + (((lane >> 3) ^ w) << 4) + ((lane & 7) << 1)) =
            wc.us;
      }
    }
    __syncthreads();  // (4) wn / final xc ready
  }

  // ---- epilogue (waves 0-7): out[b, obase+w, j=lane] = W[o][j][:]·xc ----
  if (w < 8) {
    const float* Wp = wg + ((((obase + w) << 6) + lane) << 6);
    float a0 = 0.f, a1 = 0.f, a2 = 0.f, a3 = 0.f;
#pragma unroll
    for (int k = 0; k < 16; ++k) {
      float4 wv = *reinterpret_cast<const float4*>(&Wp[k << 2]);
      float4 xv = *reinterpret_cast<const float4*>(&xc_s[(w << 6) + (k << 2)]);
      a0 += wv.x * xv.x; a1 += wv.y * xv.y;
      a2 += wv.z * xv.z; a3 += wv.w * xv.w;
    }
    outg[((b << 7) + obase + w) * 64 + lane] = (a0 + a1) + (a2 + a3);
  }
}

extern "C" void kernel_launch(void* const* d_in, const int* in_sizes, int n_in,
                              void* d_out, int out_size, void* d_ws, size_t ws_size,
                              hipStream_t stream) {
  const float* x = (const float*)d_in[0];     // (32, 512, 64) fp32
  const float* wgt = (const float*)d_in[1];   // (128, 64, 64) fp32
  float* out = (float*)d_out;                 // (32, 128, 64) fp32
  __half2* Gq = (__half2*)d_ws;               // 128*8*64 x 16B = 1 MB

  caps_gram<<<dim3(CO, 2), dim3(256), 0, stream>>>(wgt, Gq);
  caps_main<<<dim3(CO / OPB, CB), dim3(NT), 0, stream>>>(x, wgt, Gq, out);
}

// Round 17
// 39.731 us; speedup vs baseline: 1.8403x; 1.0086x over previous
//
#include <hip/hip_runtime.h>
#include <hip/hip_fp16.h>

// CapsuleLinear, B=32, I=512, L=64, O=128, J=64, 3 routing iterations.
// Algebraic fusion (no priors): out = W_o @ xc, wn = (G_o @ xc)/||W_o xc||,
// G_o = W_o^T W_o (fp16 lane-major Gq, 1 MB in d_ws).
// r17: the shape that gets BOTH 2 blocks/CU and a 128-VGPR tier is 512-thread
// blocks (2 x 8 waves = 4 waves/SIMD). amdgpu_num_vgpr(128) pins the tier
// (r16 proved the knob steers the allocator). OPB=8: wave w owns capsule w.
//  - B-frags hoisted ONCE into bt0..bt7 (32 regs, paired-dword gather)
//  - A-frags per-pass b128 from xs (conflict-free)
//  - dedicated xcpart (no coefT overlay) -> 3 barriers/pass
//  - G double-buffered 2-uint4 rounds; scale-invariant softmax (denominator
//    applied only on the last pass)
// LDS: xs 64K + coefT 8K + xcpart 4K + wn 1K + xc 2K + se 0.25K = 81152 B
// -> 2 blocks/CU; grid 512 = one full-chip resident round.

#define CB 32
#define CI 512
#define CL 64
#define CO 128
#define OPB 8
#define NT 512

typedef _Float16 half8 __attribute__((ext_vector_type(8)));
typedef float f32x4 __attribute__((ext_vector_type(4)));

static __device__ __forceinline__ _Float16 half_sel(uint v, int sh) {
  union { unsigned short s; _Float16 h; } c;
  c.s = (unsigned short)(v >> sh);
  return c.h;
}

// Gq layout (16B units): unit u = (o*8 + k)*64 + l1 holds pairs p=4k+q for
// ROW l1 (symmetric == column l1): (G[o][l1][8k+2q], G[o][l1][8k+2q+1]).
__global__ __launch_bounds__(256) void caps_gram(const float* __restrict__ wg,
                                                 __half2* __restrict__ Gq) {
  const int o = blockIdx.x;
  const int h = blockIdx.y;        // l1-half: rows h*32 .. h*32+31
  const int t = threadIdx.x;
  __shared__ float wl[64 * 65];    // W[o] padded (+1 col)
#pragma unroll
  for (int k = 0; k < 16; ++k) {
    int f = t + 256 * k;
    int j = f >> 6, l = f & 63;
    wl[j * 65 + l] = wg[(o << 12) + f];
  }
  __syncthreads();
  const int l1 = h * 32 + (t >> 3);
  const int kq = t & 7;
  const int l2b = kq << 3;
  float acc[8];
#pragma unroll
  for (int m = 0; m < 8; ++m) acc[m] = 0.f;
#pragma unroll 4
  for (int j = 0; j < 64; ++j) {
    float wa = wl[j * 65 + l1];
#pragma unroll
    for (int m = 0; m < 8; ++m) acc[m] += wa * wl[j * 65 + l2b + m];
  }
  union { __half2 h2[4]; uint4 u; } pk;
#pragma unroll
  for (int q = 0; q < 4; ++q)
    pk.h2[q] = __floats2half2_rn(acc[2 * q], acc[2 * q + 1]);
  reinterpret_cast<uint4*>(Gq)[(o << 9) + (kq << 6) + l1] = pk.u;
}

__global__ __launch_bounds__(NT)
__attribute__((amdgpu_num_vgpr(128)))
void caps_main(const float* __restrict__ xg,
               const float* __restrict__ wg,
               const __half2* __restrict__ Gq,
               float* __restrict__ outg) {
  const int b = blockIdx.y;
  const int obase = blockIdx.x * OPB;
  const int t = threadIdx.x;
  const int w = t >> 6;          // wave 0..7 == capsule o = obase + w
  const int lane = t & 63;
  const int g = lane >> 4;
  const int o15 = lane & 15;
  const int oc = o15 & 7;

  __shared__ __align__(16) _Float16 xs[CI * CL];      // 65536 B (A-frags)
  __shared__ __align__(16) _Float16 coefT[OPB * CI];  // 8192 B (unit-XOR swz)
  __shared__ __align__(16) float xcpart[2 * OPB * CL];// 4096 B [kh][o][l]
  __shared__ __align__(16) _Float16 wn16[OPB * CL];   // 1024 B (swizzled)
  __shared__ __align__(16) float xc_s[OPB * CL];      // 2048 B
  __shared__ float se_part[OPB * OPB];                // 256 B (pass 3 only)
  char* const xs_b = reinterpret_cast<char*>(xs);
  char* const cf_b = reinterpret_cast<char*>(coefT);
  char* const wn_b = reinterpret_cast<char*>(wn16);
  // total 81152 B -> 2 blocks/CU; grid 512 = one full-chip resident round

  const int kh = w >> 2, nt = w & 3;  // phase-B: K-half, l-subtile
  const int lcol = nt * 16 + o15;     // this lane's l index in phase B

  // G row pointer (16B units, coalesced across lanes); wave w = capsule w
  const uint4* Gp = reinterpret_cast<const uint4*>(Gq) +
                    ((obase + w) << 9) + lane;
  uint4 ga0, ga1;  // G double-buffer head

  // ---- stage x[b] -> fp16 subtiled LDS; coalesced float4 global reads ----
  {
    const float4* xg4 = reinterpret_cast<const float4*>(xg + b * (CI * CL));
#pragma unroll
    for (int k = 0; k < 8; ++k) {
      int f = t + NT * k;        // 8-half unit id: row i, l-unit lu
      int i = f >> 3, lu = f & 7;
      float4 a = xg4[2 * f];
      float4 c = xg4[2 * f + 1];
      union { _Float16 h[8]; uint4 u; } cv;
      cv.h[0] = (_Float16)a.x; cv.h[1] = (_Float16)a.y;
      cv.h[2] = (_Float16)a.z; cv.h[3] = (_Float16)a.w;
      cv.h[4] = (_Float16)c.x; cv.h[5] = (_Float16)c.y;
      cv.h[6] = (_Float16)c.z; cv.h[7] = (_Float16)c.w;
      int off = ((i >> 4) * 4 + (lu >> 1)) * 512 + (i & 15) * 32 + (lu & 1) * 16;
      *reinterpret_cast<uint4*>(xs_b + off) = cv.u;
    }
  }
  __syncthreads();

  // ---- setup: B-frags hoisted ONCE into bt0..bt7 + xbar partials ----
  // btK.h[j] = x[(kh*32 + K*4 + g)*8 + j][lcol]
  uint4 bt0, bt1, bt2, bt3, bt4, bt5, bt6, bt7;
  {
    const uint* xrd32 = reinterpret_cast<const uint*>(
                            xs_b + nt * 512 + ((o15 & 8) << 1)) +
                        ((o15 & 7) >> 1);
    const int sh = (o15 & 1) << 4;
    float xbs = 0.f;
#define GATHW(K, BT)                                                        \
  {                                                                         \
    int P = kh * 32 + (K)*4 + g;                                            \
    const uint* xk = xrd32 + (P >> 1) * 512 + (P & 1) * 64;                 \
    uint d0 = xk[0], d1 = xk[8], d2 = xk[16], d3 = xk[24];                  \
    uint d4 = xk[32], d5 = xk[40], d6 = xk[48], d7 = xk[56];                \
    union { _Float16 h[8]; uint4 u; } fv;                                   \
    fv.h[0] = half_sel(d0, sh); fv.h[1] = half_sel(d1, sh);                 \
    fv.h[2] = half_sel(d2, sh); fv.h[3] = half_sel(d3, sh);                 \
    fv.h[4] = half_sel(d4, sh); fv.h[5] = half_sel(d5, sh);                 \
    fv.h[6] = half_sel(d6, sh); fv.h[7] = half_sel(d7, sh);                 \
    xbs += (float)fv.h[0] + (float)fv.h[1] + (float)fv.h[2] +               \
           (float)fv.h[3] + (float)fv.h[4] + (float)fv.h[5] +               \
           (float)fv.h[6] + (float)fv.h[7];                                 \
    BT = fv.u;                                                              \
  }
    GATHW(0, bt0) GATHW(1, bt1) GATHW(2, bt2) GATHW(3, bt3)
    GATHW(4, bt4) GATHW(5, bt5) GATHW(6, bt6) GATHW(7, bt7)
#undef GATHW
    xbs += __shfl_xor(xbs, 16, 64);
    xbs += __shfl_xor(xbs, 32, 64);
    if (g == 0) xcpart[kh * 512 + lcol] = xbs;  // xbar partial at [kh][0][l]
    ga0 = Gp[0]; ga1 = Gp[64];                  // pass-0 G head
  }
  __syncthreads();

  for (int pass = 0; pass < 4; ++pass) {
    if (pass > 0) {
      // ---- phase A: logits for 8 o's via MFMA; exp -> coefT ----
      half8 bw0 = *reinterpret_cast<const half8*>(
          wn_b + oc * 128 + ((g ^ oc) << 4));
      half8 bw1 = *reinterpret_cast<const half8*>(
          wn_b + oc * 128 + (((4 + g) ^ oc) << 4));
      float sacc = 0.f;
#pragma unroll
      for (int ti = 0; ti < 4; ++ti) {
        const int st = 4 * w + ti;            // i-subtile, rows st*16..+15
        const int itb = st * 2048;
        const int abase = o15 * 32 + ((g & 1) << 4);
        half8 a0 = *reinterpret_cast<const half8*>(
            xs_b + itb + ((g >> 1) * 512) + abase);
        half8 a1 = *reinterpret_cast<const half8*>(
            xs_b + itb + ((2 + (g >> 1)) * 512) + abase);
        f32x4 d = {0.f, 0.f, 0.f, 0.f};
        d = __builtin_amdgcn_mfma_f32_16x16x32_f16(a0, bw0, d, 0, 0, 0);
        d = __builtin_amdgcn_mfma_f32_16x16x32_f16(a1, bw1, d, 0, 0, 0);
        // |logits| <= ||x_i||*sigma_max(W) ~ 2.5: softmax w/o max-sub is safe
        float e0 = __expf(d[0]), e1 = __expf(d[1]);
        float e2 = __expf(d[2]), e3 = __expf(d[3]);
        sacc += (e0 + e1) + (e2 + e3);
        if (o15 < 8) {  // valid capsule columns only
          int p = st * 2 + (g >> 1);
          union { _Float16 h[4]; uint2 u; } pk;
          pk.h[0] = (_Float16)e0; pk.h[1] = (_Float16)e1;
          pk.h[2] = (_Float16)e2; pk.h[3] = (_Float16)e3;
          *reinterpret_cast<uint2*>(cf_b + o15 * 1024 + ((p ^ o15) << 4) +
                                    ((g & 1) << 3)) = pk.u;
        }
      }
      if (pass == 3) {  // softmax denominator only needed on the final pass
        sacc += __shfl_xor(sacc, 16, 64);
        sacc += __shfl_xor(sacc, 32, 64);
        if (lane < 8) se_part[w * 8 + lane] = sacc;  // [i-wave][o]
      }
      __syncthreads();  // (1) coefT ready

      // ---- phase B: xc partials via MFMA (A=coefT b128, B=bt regs) ----
      if (pass < 3) { ga0 = Gp[0]; ga1 = Gp[64]; }  // G head in flight
      f32x4 d = {0.f, 0.f, 0.f, 0.f};
#define MFMAK(K, BT)                                                        \
  {                                                                         \
    int p = kh * 32 + (K)*4 + g;                                            \
    half8 a = *reinterpret_cast<const half8*>(cf_b + oc * 1024 +            \
                                              ((p ^ oc) << 4));             \
    d = __builtin_amdgcn_mfma_f32_16x16x32_f16(                             \
        a, *reinterpret_cast<const half8*>(&BT), d, 0, 0, 0);               \
  }
      MFMAK(0, bt0) MFMAK(1, bt1) MFMAK(2, bt2) MFMAK(3, bt3)
      MFMAK(4, bt4) MFMAK(5, bt5) MFMAK(6, bt6) MFMAK(7, bt7)
#undef MFMAK
      if (g < 2) {  // D rows 0-7 (valid o) live in lanes 0-31
#pragma unroll
        for (int r = 0; r < 4; ++r)
          xcpart[kh * 512 + (g * 4 + r) * 64 + lcol] = d[r];  // [kh][o][l]
      }
      __syncthreads();  // (2) partials ready (dedicated buffer, no overlay)
    }

    // ---- finalize (wave w = capsule w): xc; wn = G xc/||W xc|| ----
    {
      float sxc;
      if (pass == 0) {
        sxc = xcpart[lane] + xcpart[512 + lane];
      } else {
        sxc = xcpart[w * 64 + lane] + xcpart[512 + w * 64 + lane];
      }
      float xcv;
      if (pass == 3) {  // apply softmax denominator once at the end
        float sp = se_part[(lane & 7) * 8 + w];
        sp += __shfl_xor(sp, 1, 64);
        sp += __shfl_xor(sp, 2, 64);
        sp += __shfl_xor(sp, 4, 64);
        xcv = sxc / sp;
      } else {
        xcv = sxc;  // unnormalized: scale cancels inside wn
      }
      xc_s[(w << 6) + lane] = xcv;
      if (pass < 3) {
        const float4* xc4 = reinterpret_cast<const float4*>(&xc_s[w << 6]);
        float u0 = 0.f, u1 = 0.f, u2 = 0.f, u3 = 0.f;
#define GDOT(V, K)                                                          \
  {                                                                         \
    float4 xa = xc4[2 * (K)], xb = xc4[2 * (K) + 1];                        \
    float2 h0 = __half22float2(*reinterpret_cast<const __half2*>(&V.x));    \
    float2 h1 = __half22float2(*reinterpret_cast<const __half2*>(&V.y));    \
    float2 h2 = __half22float2(*reinterpret_cast<const __half2*>(&V.z));    \
    float2 h3 = __half22float2(*reinterpret_cast<const __half2*>(&V.w));    \
    u0 += h0.x * xa.x; u1 += h0.y * xa.y;                                   \
    u2 += h1.x * xa.z; u3 += h1.y * xa.w;                                   \
    u0 += h2.x * xb.x; u1 += h2.y * xb.y;                                   \
    u2 += h3.x * xb.z; u3 += h3.y * xb.w;                                   \
  }
        // double-buffered G: <=16 G regs live, loads hidden under GDOTs
        uint4 gb0 = Gp[128], gb1 = Gp[192];
        GDOT(ga0, 0) GDOT(ga1, 1)
        ga0 = Gp[256]; ga1 = Gp[320];
        GDOT(gb0, 2) GDOT(gb1, 3)
        gb0 = Gp[384]; gb1 = Gp[448];
        GDOT(ga0, 4) GDOT(ga1, 5)
        GDOT(gb0, 6) GDOT(gb1, 7)
#undef GDOT
        float uv = (u0 + u1) + (u2 + u3);
        float sq = uv * xcv;
#pragma unroll
        for (int m = 32; m; m >>= 1) sq += __shfl_xor(sq, m, 64);
        float wnv = uv / fmaxf(sqrtf(fmaxf(sq, 0.f)), 1e-12f);
        union { _Float16 hf; unsigned short us; } wc;
        wc.hf = (_Float16)wnv;
        *reinterpret_cast<unsigned short*>(
            wn_b + w * 128 + (((lane >> 3) ^ w) << 4) + ((lane & 7) << 1)) =
            wc.us;
      }
    }
    __syncthreads();  // (3) wn / final xc ready
  }

  // ---- epilogue: out[b, obase+w, j=lane] = sum_l W[o][j][l] * xc[o][l] ----
  {
    const float* Wp = wg + ((((obase + w) << 6) + lane) << 6);
    float a0 = 0.f, a1 = 0.f, a2 = 0.f, a3 = 0.f;
#pragma unroll
    for (int k = 0; k < 16; ++k) {
      float4 wv = *reinterpret_cast<const float4*>(&Wp[k << 2]);
      float4 xv = *reinterpret_cast<const float4*>(&xc_s[(w << 6) + (k << 2)]);
      a0 += wv.x * xv.x; a1 += wv.y * xv.y;
      a2 += wv.z * xv.z; a3 += wv.w * xv.w;
    }
    outg[((b << 7) + obase + w) * 64 + lane] = (a0 + a1) + (a2 + a3);
  }
}

extern "C" void kernel_launch(void* const* d_in, const int* in_sizes, int n_in,
                              void* d_out, int out_size, void* d_ws, size_t ws_size,
                              hipStream_t stream) {
  const float* x = (const float*)d_in[0];     // (32, 512, 64) fp32
  const float* wgt = (const float*)d_in[1];   // (128, 64, 64) fp32
  float* out = (float*)d_out;                 // (32, 128, 64) fp32
  __half2* Gq = (__half2*)d_ws;               // 128*8*64 x 16B = 1 MB

  caps_gram<<<dim3(CO, 2), dim3(256), 0, stream>>>(wgt, Gq);
  caps_main<<<dim3(CO / OPB, CB), dim3(NT), 0, stream>>>(x, wgt, Gq, out);
}

// Round 18
// 32.884 us; speedup vs baseline: 2.2235x; 1.2082x over previous
//
#include <hip/hip_runtime.h>
#include <hip/hip_fp16.h>

// CapsuleLinear, B=32, I=512, L=64, O=128, J=64, 3 routing iterations.
// Algebraic fusion (no priors): out = W_o @ xc, wn = (G_o @ xc)/||W_o xc||,
// G_o = W_o^T W_o (fp16 lane-major Gq, 1 MB in d_ws).
// r18 = r14 (best: 33.05 us) with ONE change: amdgpu_num_vgpr(128) replaces
// __launch_bounds__(NT,4). r16 proved the attribute steers the register-tier
// choice; at this shape (154KB LDS -> 1 block/CU -> 4 waves/SIMD) 128 VGPRs
// cost zero occupancy, and r6/r7/r10 showed (NT,4)-style bounds pin 1024-thr
// kernels at 64 VGPRs with silent spill of persistent regs (af*, ga*).
// Structure (r14, all verified): OPB=16, NT=1024, grid=256 (1 block/CU);
// xs subtiled (phase-A A-frags, hoisted once to 4 named half8); xT swizzled
// built once (phase-B B-frags b128); dedicated-xcpart-in-dead-xs (3 barriers
// per pass); G double-buffered 2-uint4 rounds; scale-invariant softmax
// (denominator applied only on the last pass).

#define CB 32
#define CI 512
#define CL 64
#define CO 128
#define OPB 16
#define NT 1024

typedef _Float16 half8 __attribute__((ext_vector_type(8)));
typedef float f32x4 __attribute__((ext_vector_type(4)));

static __device__ __forceinline__ _Float16 half_sel(uint v, int sh) {
  union { unsigned short s; _Float16 h; } c;
  c.s = (unsigned short)(v >> sh);
  return c.h;
}

// Gq layout (16B units): unit u = (o*8 + k)*64 + l1 holds pairs p=4k+q for
// ROW l1 (symmetric == column l1): (G[o][l1][8k+2q], G[o][l1][8k+2q+1]).
__global__ __launch_bounds__(256) void caps_gram(const float* __restrict__ wg,
                                                 __half2* __restrict__ Gq) {
  const int o = blockIdx.x;
  const int h = blockIdx.y;        // l1-half: rows h*32 .. h*32+31
  const int t = threadIdx.x;
  __shared__ float wl[64 * 65];    // W[o] padded (+1 col)
#pragma unroll
  for (int k = 0; k < 16; ++k) {
    int f = t + 256 * k;
    int j = f >> 6, l = f & 63;
    wl[j * 65 + l] = wg[(o << 12) + f];
  }
  __syncthreads();
  const int l1 = h * 32 + (t >> 3);
  const int kq = t & 7;
  const int l2b = kq << 3;
  float acc[8];
#pragma unroll
  for (int m = 0; m < 8; ++m) acc[m] = 0.f;
#pragma unroll 4
  for (int j = 0; j < 64; ++j) {
    float wa = wl[j * 65 + l1];
#pragma unroll
    for (int m = 0; m < 8; ++m) acc[m] += wa * wl[j * 65 + l2b + m];
  }
  union { __half2 h2[4]; uint4 u; } pk;
#pragma unroll
  for (int q = 0; q < 4; ++q)
    pk.h2[q] = __floats2half2_rn(acc[2 * q], acc[2 * q + 1]);
  reinterpret_cast<uint4*>(Gq)[(o << 9) + (kq << 6) + l1] = pk.u;
}

__global__ __launch_bounds__(NT)
__attribute__((amdgpu_num_vgpr(128)))
void caps_main(const float* __restrict__ xg,
               const float* __restrict__ wg,
               const __half2* __restrict__ Gq,
               float* __restrict__ outg) {
  const int b = blockIdx.y;
  const int obase = blockIdx.x * OPB;
  const int t = threadIdx.x;
  const int w = t >> 6;          // wave 0..15, owns capsule o = obase + w
  const int lane = t & 63;
  const int g = lane >> 4;
  const int o15 = lane & 15;

  __shared__ __align__(16) _Float16 xs[CI * CL];       // 65536 B (setup only)
  __shared__ __align__(16) _Float16 xT[CL * CI];       // 65536 B (swizzled)
  __shared__ __align__(16) _Float16 coefT[OPB * CI];   // 16384 B (dedicated)
  __shared__ __align__(16) _Float16 wn16[OPB * CL];    // 2048 B (swizzled)
  __shared__ __align__(16) float xc_s[OPB * CL];       // 4096 B
  __shared__ float se_part[OPB * OPB];                 // 1024 B (pass 3 only)
  float* const xcpart = reinterpret_cast<float*>(xs);  // 16 KB in dead xs
  char* const xs_b = reinterpret_cast<char*>(xs);
  char* const xT_b = reinterpret_cast<char*>(xT);
  char* const cf_b = reinterpret_cast<char*>(coefT);
  char* const wn_b = reinterpret_cast<char*>(wn16);
  // total 154624 B -> 1 block/CU, grid 256 = one full-chip round

  const int qh = w >> 2, nt = w & 3;  // phase-B: i-quarter, l-subtile
  const int lcol = nt * 16 + o15;     // this lane's xT row (l index)

  // G row pointer (16B units, coalesced across lanes)
  const uint4* Gp = reinterpret_cast<const uint4*>(Gq) +
                    ((obase + w) << 9) + lane;
  uint4 ga0, ga1;  // G double-buffer half (<=8 regs across barriers)

  // ---- stage x[b] -> fp16 subtiled LDS; coalesced float4 global reads ----
  {
    const float4* xg4 = reinterpret_cast<const float4*>(xg + b * (CI * CL));
#pragma unroll
    for (int k = 0; k < 4; ++k) {
      int f = t + NT * k;        // 8-half unit id: row i, l-unit lu
      int i = f >> 3, lu = f & 7;
      float4 a = xg4[2 * f];
      float4 c = xg4[2 * f + 1];
      union { _Float16 h[8]; uint4 u; } cv;
      cv.h[0] = (_Float16)a.x; cv.h[1] = (_Float16)a.y;
      cv.h[2] = (_Float16)a.z; cv.h[3] = (_Float16)a.w;
      cv.h[4] = (_Float16)c.x; cv.h[5] = (_Float16)c.y;
      cv.h[6] = (_Float16)c.z; cv.h[7] = (_Float16)c.w;
      int off = ((i >> 4) * 4 + (lu >> 1)) * 512 + (i & 15) * 32 + (lu & 1) * 16;
      *reinterpret_cast<uint4*>(xs_b + off) = cv.u;
    }
  }
  __syncthreads();

  // ---- setup: build xT once; hoist A-frags; xbar partials; G preload ----
  float xbs = 0.f;
  half8 af00, af01, af10, af11;  // phase-A A-frags, pass-invariant (16 VGPRs)
  {
    const uint* xrd32 = reinterpret_cast<const uint*>(
                            xs_b + nt * 512 + ((o15 & 8) << 1)) +
                        ((o15 & 7) >> 1);
    const int sh = (o15 & 1) << 4;
#define GATHW(K)                                                            \
  {                                                                         \
    int P = qh * 16 + (K)*4 + g;                                            \
    const uint* xk = xrd32 + (P >> 1) * 512 + (P & 1) * 64;                 \
    uint d0 = xk[0], d1 = xk[8], d2 = xk[16], d3 = xk[24];                  \
    uint d4 = xk[32], d5 = xk[40], d6 = xk[48], d7 = xk[56];                \
    union { _Float16 h[8]; uint4 u; } fv;                                   \
    fv.h[0] = half_sel(d0, sh); fv.h[1] = half_sel(d1, sh);                 \
    fv.h[2] = half_sel(d2, sh); fv.h[3] = half_sel(d3, sh);                 \
    fv.h[4] = half_sel(d4, sh); fv.h[5] = half_sel(d5, sh);                 \
    fv.h[6] = half_sel(d6, sh); fv.h[7] = half_sel(d7, sh);                 \
    xbs += (float)fv.h[0] + (float)fv.h[1] + (float)fv.h[2] +               \
           (float)fv.h[3] + (float)fv.h[4] + (float)fv.h[5] +               \
           (float)fv.h[6] + (float)fv.h[7];                                 \
    *reinterpret_cast<uint4*>(xT_b + lcol * 1024 +                          \
                              ((P ^ (lcol & 7)) << 4)) = fv.u;              \
  }
    GATHW(0) GATHW(1) GATHW(2) GATHW(3)
#undef GATHW
    // A-frags: wave w's i-subtiles st = 2w, 2w+1 (same addresses every pass)
    const int abase = (g >> 1) * 512 + o15 * 32 + ((g & 1) << 4);
    af00 = *reinterpret_cast<const half8*>(xs_b + (2 * w) * 2048 + abase);
    af01 = *reinterpret_cast<const half8*>(xs_b + (2 * w) * 2048 + 1024 + abase);
    af10 = *reinterpret_cast<const half8*>(xs_b + (2 * w + 1) * 2048 + abase);
    af11 = *reinterpret_cast<const half8*>(xs_b + (2 * w + 1) * 2048 + 1024 + abase);
    xbs += __shfl_xor(xbs, 16, 64);
    xbs += __shfl_xor(xbs, 32, 64);
    ga0 = Gp[0]; ga1 = Gp[64];  // pass-0 G first pair
  }
  __syncthreads();  // ALL xs reads complete before xcpart overlays it
  if (lane < 16) xcpart[qh * 1024 + nt * 16 + lane] = xbs;  // xbar partials

  for (int pass = 0; pass < 4; ++pass) {
    if (pass > 0) {
      // ---- phase A: logits via MFMA (A-frags from regs); exp -> coefT ----
      half8 bw0 = *reinterpret_cast<const half8*>(
          wn_b + o15 * 128 + ((g ^ (o15 & 7)) << 4));
      half8 bw1 = *reinterpret_cast<const half8*>(
          wn_b + o15 * 128 + (((4 + g) ^ (o15 & 7)) << 4));
      float sacc = 0.f;
#define PHASEA(TI, AF0, AF1)                                                \
  {                                                                         \
    const int st = 2 * w + (TI);                                            \
    f32x4 d = {0.f, 0.f, 0.f, 0.f};                                         \
    d = __builtin_amdgcn_mfma_f32_16x16x32_f16(AF0, bw0, d, 0, 0, 0);       \
    d = __builtin_amdgcn_mfma_f32_16x16x32_f16(AF1, bw1, d, 0, 0, 0);       \
    float e0 = __expf(d[0]), e1 = __expf(d[1]);                             \
    float e2 = __expf(d[2]), e3 = __expf(d[3]);                             \
    sacc += (e0 + e1) + (e2 + e3);                                          \
    int p = st * 2 + (g >> 1);                                              \
    union { _Float16 h[4]; uint2 u; } pk;                                   \
    pk.h[0] = (_Float16)e0; pk.h[1] = (_Float16)e1;                         \
    pk.h[2] = (_Float16)e2; pk.h[3] = (_Float16)e3;                         \
    *reinterpret_cast<uint2*>(cf_b + o15 * 1024 + ((p ^ o15) << 4) +        \
                              ((g & 1) << 3)) = pk.u;                       \
  }
      PHASEA(0, af00, af01)
      PHASEA(1, af10, af11)
#undef PHASEA
      if (pass == 3) {  // softmax denominator only needed on the final pass
        sacc += __shfl_xor(sacc, 16, 64);
        sacc += __shfl_xor(sacc, 32, 64);
        if (lane < 16) se_part[w * 16 + lane] = sacc;  // [i-wave][o]
      }
      __syncthreads();

      // ---- phase B: xc partials, full 16-row MFMA, b128 reads ----
      f32x4 d = {0.f, 0.f, 0.f, 0.f};
#define MFMAK(K)                                                            \
  {                                                                         \
    int p = qh * 16 + (K)*4 + g;                                            \
    half8 a = *reinterpret_cast<const half8*>(cf_b + o15 * 1024 +           \
                                              ((p ^ o15) << 4));            \
    half8 bv = *reinterpret_cast<const half8*>(xT_b + lcol * 1024 +         \
                                               ((p ^ (lcol & 7)) << 4));    \
    d = __builtin_amdgcn_mfma_f32_16x16x32_f16(a, bv, d, 0, 0, 0);          \
  }
      MFMAK(0) MFMAK(1) MFMAK(2) MFMAK(3)
#undef MFMAK
      if (pass < 3) { ga0 = Gp[0]; ga1 = Gp[64]; }  // G pair in flight
#pragma unroll
      for (int r = 0; r < 4; ++r)  // dedicated xcpart: no barrier needed
        xcpart[qh * 1024 + (g * 4 + r) * 64 + lcol] = d[r];
    }
    __syncthreads();

    // ---- finalize: xc (unnormalized until pass 3); wn = G xc/||W xc|| ----
    {
      float sxc;
      if (pass == 0) {
        sxc = xcpart[lane] + xcpart[1024 + lane] + xcpart[2048 + lane] +
              xcpart[3072 + lane];
      } else {
        sxc = xcpart[w * 64 + lane] + xcpart[1024 + w * 64 + lane] +
              xcpart[2048 + w * 64 + lane] + xcpart[3072 + w * 64 + lane];
      }
      float xcv;
      if (pass == 3) {  // apply softmax denominator once at the end
        float sp = se_part[(lane & 15) * 16 + w];
        sp += __shfl_xor(sp, 1, 64);
        sp += __shfl_xor(sp, 2, 64);
        sp += __shfl_xor(sp, 4, 64);
        sp += __shfl_xor(sp, 8, 64);
        xcv = sxc / sp;
      } else {
        xcv = sxc;  // scale cancels inside wn
      }
      xc_s[(w << 6) + lane] = xcv;
      if (pass < 3) {
        const float4* xc4 = reinterpret_cast<const float4*>(&xc_s[w << 6]);
        float u0 = 0.f, u1 = 0.f, u2 = 0.f, u3 = 0.f;
#define GDOT(V, K)                                                          \
  {                                                                         \
    float4 xa = xc4[2 * (K)], xb = xc4[2 * (K) + 1];                        \
    float2 h0 = __half22float2(*reinterpret_cast<const __half2*>(&V.x));    \
    float2 h1 = __half22float2(*reinterpret_cast<const __half2*>(&V.y));    \
    float2 h2 = __half22float2(*reinterpret_cast<const __half2*>(&V.z));    \
    float2 h3 = __half22float2(*reinterpret_cast<const __half2*>(&V.w));    \
    u0 += h0.x * xa.x; u1 += h0.y * xa.y;                                   \
    u2 += h1.x * xa.z; u3 += h1.y * xa.w;                                   \
    u0 += h2.x * xb.x; u1 += h2.y * xb.y;                                   \
    u2 += h3.x * xb.z; u3 += h3.y * xb.w;                                   \
  }
        // double-buffered G: <=16 G regs live, each load hidden under GDOTs
        uint4 gb0 = Gp[128], gb1 = Gp[192];
        GDOT(ga0, 0) GDOT(ga1, 1)
        ga0 = Gp[256]; ga1 = Gp[320];
        GDOT(gb0, 2) GDOT(gb1, 3)
        gb0 = Gp[384]; gb1 = Gp[448];
        GDOT(ga0, 4) GDOT(ga1, 5)
        GDOT(gb0, 6) GDOT(gb1, 7)
#undef GDOT
        float uv = (u0 + u1) + (u2 + u3);
        float sq = uv * xcv;
#pragma unroll
        for (int m = 32; m; m >>= 1) sq += __shfl_xor(sq, m, 64);
        float wnv = uv / fmaxf(sqrtf(fmaxf(sq, 0.f)), 1e-12f);
        union { _Float16 hf; unsigned short us; } wc;
        wc.hf = (_Float16)wnv;
        *reinterpret_cast<unsigned short*>(
            wn_b + w * 128 + (((lane >> 3) ^ (w & 7)) << 4) +
            ((lane & 7) << 1)) = wc.us;
      }
    }
    __syncthreads();
  }

  // ---- epilogue: out[b, obase+w, j=lane] = sum_l W[o][j][l] * xc[o][l] ----
  {
    const float* Wp = wg + ((((obase + w) << 6) + lane) << 6);
    float a0 = 0.f, a1 = 0.f, a2 = 0.f, a3 = 0.f;
#pragma unroll
    for (int k = 0; k < 16; ++k) {
      float4 wv = *reinterpret_cast<const float4*>(&Wp[k << 2]);
      float4 xv = *reinterpret_cast<const float4*>(&xc_s[(w << 6) + (k << 2)]);
      a0 += wv.x * xv.x; a1 += wv.y * xv.y;
      a2 += wv.z * xv.z; a3 += wv.w * xv.w;
    }
    outg[((b << 7) + obase + w) * 64 + lane] = (a0 + a1) + (a2 + a3);
  }
}

extern "C" void kernel_launch(void* const* d_in, const int* in_sizes, int n_in,
                              void* d_out, int out_size, void* d_ws, size_t ws_size,
                              hipStream_t stream) {
  const float* x = (const float*)d_in[0];     // (32, 512, 64) fp32
  const float* wgt = (const float*)d_in[1];   // (128, 64, 64) fp32
  float* out = (float*)d_out;                 // (32, 128, 64) fp32
  __half2* Gq = (__half2*)d_ws;               // 128*8*64 x 16B = 1 MB

  caps_gram<<<dim3(CO, 2), dim3(256), 0, stream>>>(wgt, Gq);
  caps_main<<<dim3(CO / OPB, CB), dim3(NT), 0, stream>>>(x, wgt, Gq, out);
}

// Round 19
// 32.152 us; speedup vs baseline: 2.2741x; 1.0228x over previous
//
#include <hip/hip_runtime.h>
#include <hip/hip_fp16.h>

// CapsuleLinear, B=32, I=512, L=64, O=128, J=64, 3 routing iterations.
// Algebraic fusion (no priors): out = W_o @ xc, wn = (G_o @ xc)/||W_o xc||,
// G_o = W_o^T W_o (fp16 lane-major Gq, 1 MB in d_ws).
// r19 = r18 (32.88 us) minus the xT LDS round-trip: each lane's phase-B
// B-fragments are exactly the 4 uint4 it gathered in setup (same qh/nt/g/o15
// indices on write and read), so they live in named registers bt0..bt3.
// amdgpu_num_vgpr(128) (r16/r18-proven at this shape) protects the alloc:
// persistent = af* 16 + bt* 16 + ga* 8 = 40 regs, zero occupancy cost at
// 1 block/CU. Saves 4 b128 LDS reads/lane/pass + setup writes, -64 KB LDS.
// Structure otherwise r14/r18: OPB=16, NT=1024, grid=256 (1 block/CU);
// A-frags hoisted to 4 named half8; dedicated-xcpart-in-dead-xs; G
// double-buffered; scale-invariant softmax (denominator on last pass only).

#define CB 32
#define CI 512
#define CL 64
#define CO 128
#define OPB 16
#define NT 1024

typedef _Float16 half8 __attribute__((ext_vector_type(8)));
typedef float f32x4 __attribute__((ext_vector_type(4)));

static __device__ __forceinline__ _Float16 half_sel(uint v, int sh) {
  union { unsigned short s; _Float16 h; } c;
  c.s = (unsigned short)(v >> sh);
  return c.h;
}

// Gq layout (16B units): unit u = (o*8 + k)*64 + l1 holds pairs p=4k+q for
// ROW l1 (symmetric == column l1): (G[o][l1][8k+2q], G[o][l1][8k+2q+1]).
__global__ __launch_bounds__(256) void caps_gram(const float* __restrict__ wg,
                                                 __half2* __restrict__ Gq) {
  const int o = blockIdx.x;
  const int h = blockIdx.y;        // l1-half: rows h*32 .. h*32+31
  const int t = threadIdx.x;
  __shared__ float wl[64 * 65];    // W[o] padded (+1 col)
#pragma unroll
  for (int k = 0; k < 16; ++k) {
    int f = t + 256 * k;
    int j = f >> 6, l = f & 63;
    wl[j * 65 + l] = wg[(o << 12) + f];
  }
  __syncthreads();
  const int l1 = h * 32 + (t >> 3);
  const int kq = t & 7;
  const int l2b = kq << 3;
  float acc[8];
#pragma unroll
  for (int m = 0; m < 8; ++m) acc[m] = 0.f;
#pragma unroll 4
  for (int j = 0; j < 64; ++j) {
    float wa = wl[j * 65 + l1];
#pragma unroll
    for (int m = 0; m < 8; ++m) acc[m] += wa * wl[j * 65 + l2b + m];
  }
  union { __half2 h2[4]; uint4 u; } pk;
#pragma unroll
  for (int q = 0; q < 4; ++q)
    pk.h2[q] = __floats2half2_rn(acc[2 * q], acc[2 * q + 1]);
  reinterpret_cast<uint4*>(Gq)[(o << 9) + (kq << 6) + l1] = pk.u;
}

__global__ __launch_bounds__(NT)
__attribute__((amdgpu_num_vgpr(128)))
void caps_main(const float* __restrict__ xg,
               const float* __restrict__ wg,
               const __half2* __restrict__ Gq,
               float* __restrict__ outg) {
  const int b = blockIdx.y;
  const int obase = blockIdx.x * OPB;
  const int t = threadIdx.x;
  const int w = t >> 6;          // wave 0..15, owns capsule o = obase + w
  const int lane = t & 63;
  const int g = lane >> 4;
  const int o15 = lane & 15;

  __shared__ __align__(16) _Float16 xs[CI * CL];       // 65536 B (setup only)
  __shared__ __align__(16) _Float16 coefT[OPB * CI];   // 16384 B (dedicated)
  __shared__ __align__(16) _Float16 wn16[OPB * CL];    // 2048 B (swizzled)
  __shared__ __align__(16) float xc_s[OPB * CL];       // 4096 B
  __shared__ float se_part[OPB * OPB];                 // 1024 B (pass 3 only)
  float* const xcpart = reinterpret_cast<float*>(xs);  // 16 KB in dead xs
  char* const xs_b = reinterpret_cast<char*>(xs);
  char* const cf_b = reinterpret_cast<char*>(coefT);
  char* const wn_b = reinterpret_cast<char*>(wn16);
  // total 89088 B -> 1 block/CU, grid 256 = one full-chip round

  const int qh = w >> 2, nt = w & 3;  // phase-B: i-quarter, l-subtile
  const int lcol = nt * 16 + o15;     // this lane's l index in phase B

  // G row pointer (16B units, coalesced across lanes)
  const uint4* Gp = reinterpret_cast<const uint4*>(Gq) +
                    ((obase + w) << 9) + lane;
  uint4 ga0, ga1;  // G double-buffer half (<=8 regs across barriers)

  // ---- stage x[b] -> fp16 subtiled LDS; coalesced float4 global reads ----
  {
    const float4* xg4 = reinterpret_cast<const float4*>(xg + b * (CI * CL));
#pragma unroll
    for (int k = 0; k < 4; ++k) {
      int f = t + NT * k;        // 8-half unit id: row i, l-unit lu
      int i = f >> 3, lu = f & 7;
      float4 a = xg4[2 * f];
      float4 c = xg4[2 * f + 1];
      union { _Float16 h[8]; uint4 u; } cv;
      cv.h[0] = (_Float16)a.x; cv.h[1] = (_Float16)a.y;
      cv.h[2] = (_Float16)a.z; cv.h[3] = (_Float16)a.w;
      cv.h[4] = (_Float16)c.x; cv.h[5] = (_Float16)c.y;
      cv.h[6] = (_Float16)c.z; cv.h[7] = (_Float16)c.w;
      int off = ((i >> 4) * 4 + (lu >> 1)) * 512 + (i & 15) * 32 + (lu & 1) * 16;
      *reinterpret_cast<uint4*>(xs_b + off) = cv.u;
    }
  }
  __syncthreads();

  // ---- setup: gather B-frags into bt0..bt3; hoist A-frags; xbar; G ----
  // btK.h[j] = x[(qh*16 + K*4 + g)*8 + j][lcol]  (kept in registers; the
  // r14/r18 xT write+read used identical indices -> pure round-trip)
  float xbs = 0.f;
  half8 af00, af01, af10, af11;  // phase-A A-frags, pass-invariant (16 VGPRs)
  uint4 bt0, bt1, bt2, bt3;      // phase-B B-frags, pass-invariant (16 VGPRs)
  {
    const uint* xrd32 = reinterpret_cast<const uint*>(
                            xs_b + nt * 512 + ((o15 & 8) << 1)) +
                        ((o15 & 7) >> 1);
    const int sh = (o15 & 1) << 4;
#define GATHW(K, BT)                                                        \
  {                                                                         \
    int P = qh * 16 + (K)*4 + g;                                            \
    const uint* xk = xrd32 + (P >> 1) * 512 + (P & 1) * 64;                 \
    uint d0 = xk[0], d1 = xk[8], d2 = xk[16], d3 = xk[24];                  \
    uint d4 = xk[32], d5 = xk[40], d6 = xk[48], d7 = xk[56];                \
    union { _Float16 h[8]; uint4 u; } fv;                                   \
    fv.h[0] = half_sel(d0, sh); fv.h[1] = half_sel(d1, sh);                 \
    fv.h[2] = half_sel(d2, sh); fv.h[3] = half_sel(d3, sh);                 \
    fv.h[4] = half_sel(d4, sh); fv.h[5] = half_sel(d5, sh);                 \
    fv.h[6] = half_sel(d6, sh); fv.h[7] = half_sel(d7, sh);                 \
    xbs += (float)fv.h[0] + (float)fv.h[1] + (float)fv.h[2] +               \
           (float)fv.h[3] + (float)fv.h[4] + (float)fv.h[5] +               \
           (float)fv.h[6] + (float)fv.h[7];                                 \
    BT = fv.u;                                                              \
  }
    GATHW(0, bt0) GATHW(1, bt1) GATHW(2, bt2) GATHW(3, bt3)
#undef GATHW
    // A-frags: wave w's i-subtiles st = 2w, 2w+1 (same addresses every pass)
    const int abase = (g >> 1) * 512 + o15 * 32 + ((g & 1) << 4);
    af00 = *reinterpret_cast<const half8*>(xs_b + (2 * w) * 2048 + abase);
    af01 = *reinterpret_cast<const half8*>(xs_b + (2 * w) * 2048 + 1024 + abase);
    af10 = *reinterpret_cast<const half8*>(xs_b + (2 * w + 1) * 2048 + abase);
    af11 = *reinterpret_cast<const half8*>(xs_b + (2 * w + 1) * 2048 + 1024 + abase);
    xbs += __shfl_xor(xbs, 16, 64);
    xbs += __shfl_xor(xbs, 32, 64);
    ga0 = Gp[0]; ga1 = Gp[64];  // pass-0 G first pair
  }
  __syncthreads();  // ALL xs reads complete before xcpart overlays it
  if (lane < 16) xcpart[qh * 1024 + nt * 16 + lane] = xbs;  // xbar partials

  for (int pass = 0; pass < 4; ++pass) {
    if (pass > 0) {
      // ---- phase A: logits via MFMA (A-frags from regs); exp -> coefT ----
      half8 bw0 = *reinterpret_cast<const half8*>(
          wn_b + o15 * 128 + ((g ^ (o15 & 7)) << 4));
      half8 bw1 = *reinterpret_cast<const half8*>(
          wn_b + o15 * 128 + (((4 + g) ^ (o15 & 7)) << 4));
      float sacc = 0.f;
#define PHASEA(TI, AF0, AF1)                                                \
  {                                                                         \
    const int st = 2 * w + (TI);                                            \
    f32x4 d = {0.f, 0.f, 0.f, 0.f};                                         \
    d = __builtin_amdgcn_mfma_f32_16x16x32_f16(AF0, bw0, d, 0, 0, 0);       \
    d = __builtin_amdgcn_mfma_f32_16x16x32_f16(AF1, bw1, d, 0, 0, 0);       \
    float e0 = __expf(d[0]), e1 = __expf(d[1]);                             \
    float e2 = __expf(d[2]), e3 = __expf(d[3]);                             \
    sacc += (e0 + e1) + (e2 + e3);                                          \
    int p = st * 2 + (g >> 1);                                              \
    union { _Float16 h[4]; uint2 u; } pk;                                   \
    pk.h[0] = (_Float16)e0; pk.h[1] = (_Float16)e1;                         \
    pk.h[2] = (_Float16)e2; pk.h[3] = (_Float16)e3;                         \
    *reinterpret_cast<uint2*>(cf_b + o15 * 1024 + ((p ^ o15) << 4) +        \
                              ((g & 1) << 3)) = pk.u;                       \
  }
      PHASEA(0, af00, af01)
      PHASEA(1, af10, af11)
#undef PHASEA
      if (pass == 3) {  // softmax denominator only needed on the final pass
        sacc += __shfl_xor(sacc, 16, 64);
        sacc += __shfl_xor(sacc, 32, 64);
        if (lane < 16) se_part[w * 16 + lane] = sacc;  // [i-wave][o]
      }
      __syncthreads();

      // ---- phase B: xc partials, full 16-row MFMA (A b128, B regs) ----
      f32x4 d = {0.f, 0.f, 0.f, 0.f};
#define MFMAK(K, BT)                                                        \
  {                                                                         \
    int p = qh * 16 + (K)*4 + g;                                            \
    half8 a = *reinterpret_cast<const half8*>(cf_b + o15 * 1024 +           \
                                              ((p ^ o15) << 4));            \
    d = __builtin_amdgcn_mfma_f32_16x16x32_f16(                             \
        a, *reinterpret_cast<const half8*>(&BT), d, 0, 0, 0);               \
  }
      MFMAK(0, bt0) MFMAK(1, bt1) MFMAK(2, bt2) MFMAK(3, bt3)
#undef MFMAK
      if (pass < 3) { ga0 = Gp[0]; ga1 = Gp[64]; }  // G pair in flight
#pragma unroll
      for (int r = 0; r < 4; ++r)  // dedicated xcpart: no barrier needed
        xcpart[qh * 1024 + (g * 4 + r) * 64 + lcol] = d[r];
    }
    __syncthreads();

    // ---- finalize: xc (unnormalized until pass 3); wn = G xc/||W xc|| ----
    {
      float sxc;
      if (pass == 0) {
        sxc = xcpart[lane] + xcpart[1024 + lane] + xcpart[2048 + lane] +
              xcpart[3072 + lane];
      } else {
        sxc = xcpart[w * 64 + lane] + xcpart[1024 + w * 64 + lane] +
              xcpart[2048 + w * 64 + lane] + xcpart[3072 + w * 64 + lane];
      }
      float xcv;
      if (pass == 3) {  // apply softmax denominator once at the end
        float sp = se_part[(lane & 15) * 16 + w];
        sp += __shfl_xor(sp, 1, 64);
        sp += __shfl_xor(sp, 2, 64);
        sp += __shfl_xor(sp, 4, 64);
        sp += __shfl_xor(sp, 8, 64);
        xcv = sxc / sp;
      } else {
        xcv = sxc;  // scale cancels inside wn
      }
      xc_s[(w << 6) + lane] = xcv;
      if (pass < 3) {
        const float4* xc4 = reinterpret_cast<const float4*>(&xc_s[w << 6]);
        float u0 = 0.f, u1 = 0.f, u2 = 0.f, u3 = 0.f;
#define GDOT(V, K)                                                          \
  {                                                                         \
    float4 xa = xc4[2 * (K)], xb = xc4[2 * (K) + 1];                        \
    float2 h0 = __half22float2(*reinterpret_cast<const __half2*>(&V.x));    \
    float2 h1 = __half22float2(*reinterpret_cast<const __half2*>(&V.y));    \
    float2 h2 = __half22float2(*reinterpret_cast<const __half2*>(&V.z));    \
    float2 h3 = __half22float2(*reinterpret_cast<const __half2*>(&V.w));    \
    u0 += h0.x * xa.x; u1 += h0.y * xa.y;                                   \
    u2 += h1.x * xa.z; u3 += h1.y * xa.w;                                   \
    u0 += h2.x * xb.x; u1 += h2.y * xb.y;                                   \
    u2 += h3.x * xb.z; u3 += h3.y * xb.w;                                   \
  }
        // double-buffered G: <=16 G regs live, each load hidden under GDOTs
        uint4 gb0 = Gp[128], gb1 = Gp[192];
        GDOT(ga0, 0) GDOT(ga1, 1)
        ga0 = Gp[256]; ga1 = Gp[320];
        GDOT(gb0, 2) GDOT(gb1, 3)
        gb0 = Gp[384]; gb1 = Gp[448];
        GDOT(ga0, 4) GDOT(ga1, 5)
        GDOT(gb0, 6) GDOT(gb1, 7)
#undef GDOT
        float uv = (u0 + u1) + (u2 + u3);
        float sq = uv * xcv;
#pragma unroll
        for (int m = 32; m; m >>= 1) sq += __shfl_xor(sq, m, 64);
        float wnv = uv / fmaxf(sqrtf(fmaxf(sq, 0.f)), 1e-12f);
        union { _Float16 hf; unsigned short us; } wc;
        wc.hf = (_Float16)wnv;
        *reinterpret_cast<unsigned short*>(
            wn_b + w * 128 + (((lane >> 3) ^ (w & 7)) << 4) +
            ((lane & 7) << 1)) = wc.us;
      }
    }
    __syncthreads();
  }

  // ---- epilogue: out[b, obase+w, j=lane] = sum_l W[o][j][l] * xc[o][l] ----
  {
    const float* Wp = wg + ((((obase + w) << 6) + lane) << 6);
    float a0 = 0.f, a1 = 0.f, a2 = 0.f, a3 = 0.f;
#pragma unroll
    for (int k = 0; k < 16; ++k) {
      float4 wv = *reinterpret_cast<const float4*>(&Wp[k << 2]);
      float4 xv = *reinterpret_cast<const float4*>(&xc_s[(w << 6) + (k << 2)]);
      a0 += wv.x * xv.x; a1 += wv.y * xv.y;
      a2 += wv.z * xv.z; a3 += wv.w * xv.w;
    }
    outg[((b << 7) + obase + w) * 64 + lane] = (a0 + a1) + (a2 + a3);
  }
}

extern "C" void kernel_launch(void* const* d_in, const int* in_sizes, int n_in,
                              void* d_out, int out_size, void* d_ws, size_t ws_size,
                              hipStream_t stream) {
  const float* x = (const float*)d_in[0];     // (32, 512, 64) fp32
  const float* wgt = (const float*)d_in[1];   // (128, 64, 64) fp32
  float* out = (float*)d_out;                 // (32, 128, 64) fp32
  __half2* Gq = (__half2*)d_ws;               // 128*8*64 x 16B = 1 MB

  caps_gram<<<dim3(CO, 2), dim3(256), 0, stream>>>(wgt, Gq);
  caps_main<<<dim3(CO / OPB, CB), dim3(NT), 0, stream>>>(x, wgt, Gq, out);
}